// Round 3
// baseline (271.615 us; speedup 1.0000x reference)
//
#include <hip/hip_runtime.h>
#include <math.h>

#define H_IMG 1024
#define W_IMG 1280
#define NPIX (H_IMG * W_IMG)
#define NQUAD (NPIX / 4)          // 327680
#define RTPB 256
#define RBLOCKS (NQUAD / RTPB)    // 1280 blocks, exactly 1 quad (4 px) per thread
#define NACC 28                   // 21 JtJ upper-tri + 6 JtR + 1 count
#define NREP 8                    // atomic replicas (chain = RBLOCKS/NREP = 160)
#define NORM_THR 0.93969262f      // float(cos(20 deg))
#define DIST_THR2 0.04f           // 0.2^2
#define DAMPING 1e-6

// ws layout (doubles): [0..15] pose (f64)
//                      [16 .. 16+NREP*NACC*8) acc slots, each on its own 64B line
//                      then one unsigned counter
#define ACC_DOUBLES (NREP * NACC * 8)

// ---------------------------------------------------------------------------
__global__ __launch_bounds__(256) void icp_init(const float* __restrict__ pose_in,
                                                double* __restrict__ ws) {
    const int i = threadIdx.x;
    if (i < 16) ws[i] = (double)pose_in[i];
    for (int k = i; k < ACC_DOUBLES; k += 256) ws[16 + k] = 0.0;
    if (i == 0) *(unsigned*)(ws + 16 + ACC_DOUBLES) = 0u;
}

// ---------------------------------------------------------------------------
// 6x6 damped solve + exp_se3 + pose update, single thread, f64.
__device__ void solve_and_update(const double* tot, double* pose_ws,
                                 float* out, int write_out) {
    double JtJ[6][6];
    {
        int k = 0;
        for (int i = 0; i < 6; ++i)
            for (int j = i; j < 6; ++j) { JtJ[i][j] = tot[k]; JtJ[j][i] = tot[k]; ++k; }
    }
    double tr = 0.0;
    for (int i = 0; i < 6; ++i) tr += JtJ[i][i];

    double A[6][7];
    for (int i = 0; i < 6; ++i) {
        for (int j = 0; j < 6; ++j) A[i][j] = JtJ[i][j] + (i == j ? tr * DAMPING : 0.0);
        A[i][6] = -tot[21 + i];
    }
    for (int c = 0; c < 6; ++c) {
        int piv = c; double mx = fabs(A[c][c]);
        for (int r = c + 1; r < 6; ++r) {
            double ar = fabs(A[r][c]);
            if (ar > mx) { mx = ar; piv = r; }
        }
        if (piv != c) for (int j = 0; j < 7; ++j) { double tmp = A[c][j]; A[c][j] = A[piv][j]; A[piv][j] = tmp; }
        double d = A[c][c]; if (d == 0.0) d = 1e-30;
        for (int r = c + 1; r < 6; ++r) {
            double f = A[r][c] / d;
            for (int j = c; j < 7; ++j) A[r][j] -= f * A[c][j];
        }
    }
    double xi[6];
    for (int i = 5; i >= 0; --i) {
        double s = A[i][6];
        for (int j = i + 1; j < 6; ++j) s -= A[i][j] * xi[j];
        double d = A[i][i]; if (d == 0.0) d = 1e-30;
        xi[i] = s / d;
    }

    const double w0 = xi[0], w1 = xi[1], w2 = xi[2];
    const double v0 = xi[3], v1 = xi[4], v2 = xi[5];
    double wh[3][3] = { {0.0, -w2, w1}, {w2, 0.0, -w0}, {-w1, w0, 0.0} };
    double wh2[3][3];
    for (int i = 0; i < 3; ++i)
        for (int j = 0; j < 3; ++j) {
            double s = 0.0;
            for (int k = 0; k < 3; ++k) s += wh[i][k] * wh[k][j];
            wh2[i][j] = s;
        }
    const double theta = sqrt(w0 * w0 + w1 * w1 + w2 * w2);
    const double eps = 1e-8;
    const double ts = (theta > eps) ? theta : eps;
    const double st = sin(ts), ct = cos(ts);
    const double cA = st / ts;
    const double cB = (1.0 - ct) / (ts * ts);
    const double cC = (ts - st) / (ts * ts * ts);
    const bool small = (theta <= eps);

    double ew[3][3], Jm[3][3];
    for (int i = 0; i < 3; ++i)
        for (int j = 0; j < 3; ++j) {
            double eye = (i == j) ? 1.0 : 0.0;
            ew[i][j] = small ? eye : (eye + cA * wh[i][j] + cB * wh2[i][j]);
            Jm[i][j] = small ? eye : (eye + cB * wh[i][j] + cC * wh2[i][j]);
        }
    double Jv[3];
    for (int i = 0; i < 3; ++i) Jv[i] = Jm[i][0] * v0 + Jm[i][1] * v1 + Jm[i][2] * v2;

    double T[16] = { ew[0][0], ew[0][1], ew[0][2], Jv[0],
                     ew[1][0], ew[1][1], ew[1][2], Jv[1],
                     ew[2][0], ew[2][1], ew[2][2], Jv[2],
                     0.0, 0.0, 0.0, 1.0 };
    double P[16];
    for (int i = 0; i < 16; ++i) P[i] = pose_ws[i];
    double NP[16];
    for (int i = 0; i < 4; ++i)
        for (int j = 0; j < 4; ++j) {
            double s = 0.0;
            for (int k = 0; k < 4; ++k) s += T[i * 4 + k] * P[k * 4 + j];
            NP[i * 4 + j] = s;
        }
    for (int i = 0; i < 16; ++i) pose_ws[i] = NP[i];

    if (write_out) {
        for (int i = 0; i < 16; ++i) out[i] = (float)NP[i];
        out[16] = (float)(tot[27] / (double)NPIX);
    }
}

// ---------------------------------------------------------------------------
__global__ __launch_bounds__(RTPB) void icp_fused(
    const float* __restrict__ vert0, const float* __restrict__ vert1,
    const float* __restrict__ norm0, const float* __restrict__ norm1,
    const float* __restrict__ Kmat, double* __restrict__ ws,
    float* __restrict__ out, int write_out)
{
    const double* pose = ws;
    double* acc = ws + 16;
    unsigned* counter = (unsigned*)(ws + 16 + ACC_DOUBLES);

    const float R00 = (float)pose[0],  R01 = (float)pose[1],  R02 = (float)pose[2],  t0 = (float)pose[3];
    const float R10 = (float)pose[4],  R11 = (float)pose[5],  R12 = (float)pose[6],  t1 = (float)pose[7];
    const float R20 = (float)pose[8],  R21 = (float)pose[9],  R22 = (float)pose[10], t2 = (float)pose[11];
    const float fx = Kmat[0], cx = Kmat[2], fy = Kmat[4], cy = Kmat[5];

    float a[NACC];
#pragma unroll
    for (int k = 0; k < NACC; ++k) a[k] = 0.0f;

    auto do_pixel = [&](float v0x, float v0y, float v0z,
                        float n0x, float n0y, float n0z) {
        const float px = R00 * v0x + R01 * v0y + R02 * v0z + t0;
        const float py = R10 * v0x + R11 * v0y + R12 * v0z + t1;
        const float pz = R20 * v0x + R21 * v0y + R22 * v0z + t2;
        const float nrx = R00 * n0x + R01 * n0y + R02 * n0z;
        const float nry = R10 * n0x + R11 * n0y + R12 * n0z;
        const float nrz = R20 * n0x + R21 * n0y + R22 * n0z;

        const float u = px / pz * fx + cx;
        const float v = py / pz * fy + cy;
        const bool inview = (u > 0.0f) && (u < (float)(W_IMG - 1)) &&
                            (v > 0.0f) && (v < (float)(H_IMG - 1));

        const float uf = fminf(fmaxf(rintf(u), 0.0f), (float)(W_IMG - 1));
        const float vf = fminf(fmaxf(rintf(v), 0.0f), (float)(H_IMG - 1));
        const int wbase = ((int)vf * W_IMG + (int)uf) * 3;

        const float r1x = vert1[wbase], r1y = vert1[wbase + 1], r1z = vert1[wbase + 2];
        const float m1x = norm1[wbase], m1y = norm1[wbase + 1], m1z = norm1[wbase + 2];

        const float dx = px - r1x, dy = py - r1y, dz = pz - r1z;
        const bool mask0 = v0z > 0.0f;
        const bool mask1 = r1z > 0.0f;
        const bool normal_ok = (nrx * m1x + nry * m1y + nrz * m1z) > NORM_THR;
        const float d2 = dx * dx + dy * dy + dz * dz;
        const bool occ = (!inview) || (d2 > DIST_THR2);
        const bool valid = (!occ) && mask0 && mask1 && normal_ok;

        if (valid) {
            const float res = m1x * dx + m1y * dy + m1z * dz;
            float J[6];
            J[0] = py * m1z - pz * m1y;
            J[1] = pz * m1x - px * m1z;
            J[2] = px * m1y - py * m1x;
            J[3] = m1x; J[4] = m1y; J[5] = m1z;
            int k = 0;
#pragma unroll
            for (int i = 0; i < 6; ++i)
#pragma unroll
                for (int j = i; j < 6; ++j) a[k++] += J[i] * J[j];
#pragma unroll
            for (int i = 0; i < 6; ++i) a[21 + i] += J[i] * res;
            a[27] += 1.0f;
        }
    };

    // exactly one quad (4 pixels) per thread
    const int q = blockIdx.x * RTPB + threadIdx.x;
    const float4* v0q = (const float4*)vert0;
    const float4* n0q = (const float4*)norm0;
    const float4 A0 = v0q[q * 3 + 0], A1 = v0q[q * 3 + 1], A2 = v0q[q * 3 + 2];
    const float4 B0 = n0q[q * 3 + 0], B1 = n0q[q * 3 + 1], B2 = n0q[q * 3 + 2];
    do_pixel(A0.x, A0.y, A0.z, B0.x, B0.y, B0.z);
    do_pixel(A0.w, A1.x, A1.y, B0.w, B1.x, B1.y);
    do_pixel(A1.z, A1.w, A2.x, B1.z, B1.w, B2.x);
    do_pixel(A2.y, A2.z, A2.w, B2.y, B2.z, B2.w);

    // wave-64 tree reduction per component
#pragma unroll
    for (int k = 0; k < NACC; ++k) {
        float val = a[k];
        for (int off = 32; off > 0; off >>= 1) val += __shfl_down(val, off, 64);
        a[k] = val;
    }

    __shared__ float sh[4][NACC];
    const int lane = threadIdx.x & 63;
    const int wid  = threadIdx.x >> 6;
    if (lane == 0) {
#pragma unroll
        for (int k = 0; k < NACC; ++k) sh[wid][k] = a[k];
    }
    __syncthreads();

    const unsigned tid = threadIdx.x;
    const int rep = blockIdx.x & (NREP - 1);
    if (tid < NACC) {
        double s = (double)sh[0][tid] + (double)sh[1][tid] +
                   (double)sh[2][tid] + (double)sh[3][tid];
        atomicAdd(&acc[(rep * NACC + (int)tid) * 8], s);
        __threadfence();   // my atomic globally visible before the ticket
    }
    __syncthreads();

    __shared__ bool amLast;
    if (tid == 0) {
        unsigned prev = atomicAdd(counter, 1u);
        amLast = (prev == gridDim.x - 1);
    }
    __syncthreads();

    if (amLast) {
        // parallel readback: one coherent round-trip for all NREP*NACC slots
        __shared__ double shd[NREP][NACC];
        __shared__ double tot[NACC];
        if (tid < NREP * NACC) {
            const int r = (int)tid / NACC;
            const int k = (int)tid % NACC;
            shd[r][k] = atomicAdd(&acc[(r * NACC + k) * 8], 0.0);  // coherent read
            atomicExch((unsigned long long*)&acc[(r * NACC + k) * 8], 0ull);  // re-zero
        }
        if (tid == 0) atomicExch(counter, 0u);
        __syncthreads();
        if (tid < NACC) {
            double s = 0.0;
#pragma unroll
            for (int r = 0; r < NREP; ++r) s += shd[r][tid];
            tot[tid] = s;
        }
        __syncthreads();
        if (tid == 0) solve_and_update(tot, ws, out, write_out);
    }
}

// ---------------------------------------------------------------------------
extern "C" void kernel_launch(void* const* d_in, const int* in_sizes, int n_in,
                              void* d_out, int out_size, void* d_ws, size_t ws_size,
                              hipStream_t stream) {
    const float* pose10 = (const float*)d_in[0];
    const float* vert0  = (const float*)d_in[1];
    const float* vert1  = (const float*)d_in[2];
    const float* norm0  = (const float*)d_in[3];
    const float* norm1  = (const float*)d_in[4];
    const float* Kmat   = (const float*)d_in[5];
    float* out = (float*)d_out;
    double* ws = (double*)d_ws;

    icp_init<<<1, 256, 0, stream>>>(pose10, ws);
    for (int it = 0; it < 3; ++it) {
        icp_fused<<<RBLOCKS, RTPB, 0, stream>>>(vert0, vert1, norm0, norm1,
                                                Kmat, ws, out, it == 2 ? 1 : 0);
    }
}

// Round 4
// 243.648 us; speedup vs baseline: 1.1148x; 1.1148x over previous
//
#include <hip/hip_runtime.h>
#include <math.h>

#define H_IMG 1024
#define W_IMG 1280
#define NPIX (H_IMG * W_IMG)
#define NQUAD (NPIX / 4)          // 327680
#define RTPB 256
#define RBLOCKS (NQUAD / RTPB)    // 1280 blocks, exactly 1 quad (4 px) per thread
#define NACC 28                   // 21 JtJ upper-tri + 6 JtR + 1 count
#define NORM_THR 0.93969262f      // float(cos(20 deg))
#define DIST_THR2 0.04f           // 0.2^2
#define DAMPING 1e-6

// ws layout: doubles [0..15] = pose (f64); then float partials[RBLOCKS*NACC]
// (plain stores, fully overwritten every reduce -> no init/memset needed)

// ---------------------------------------------------------------------------
// reduce: per-pixel residual/Jacobian -> per-block 28 f32 partials (plain store)
// ---------------------------------------------------------------------------
__global__ __launch_bounds__(RTPB) void icp_reduce(
    const float* __restrict__ vert0, const float* __restrict__ vert1,
    const float* __restrict__ norm0, const float* __restrict__ norm1,
    const float* __restrict__ Kmat, const float* __restrict__ pose0_f32,
    const double* __restrict__ pose_f64, float* __restrict__ partials,
    int first)
{
    float P[12];
    if (first) {
#pragma unroll
        for (int i = 0; i < 12; ++i) P[i] = pose0_f32[i];
    } else {
#pragma unroll
        for (int i = 0; i < 12; ++i) P[i] = (float)pose_f64[i];
    }
    const float R00 = P[0], R01 = P[1],  R02 = P[2],  t0 = P[3];
    const float R10 = P[4], R11 = P[5],  R12 = P[6],  t1 = P[7];
    const float R20 = P[8], R21 = P[9],  R22 = P[10], t2 = P[11];
    const float fx = Kmat[0], cx = Kmat[2], fy = Kmat[4], cy = Kmat[5];

    float a[NACC];
#pragma unroll
    for (int k = 0; k < NACC; ++k) a[k] = 0.0f;

    auto do_pixel = [&](float v0x, float v0y, float v0z,
                        float n0x, float n0y, float n0z) {
        const float px = R00 * v0x + R01 * v0y + R02 * v0z + t0;
        const float py = R10 * v0x + R11 * v0y + R12 * v0z + t1;
        const float pz = R20 * v0x + R21 * v0y + R22 * v0z + t2;
        const float nrx = R00 * n0x + R01 * n0y + R02 * n0z;
        const float nry = R10 * n0x + R11 * n0y + R12 * n0z;
        const float nrz = R20 * n0x + R21 * n0y + R22 * n0z;

        const float u = px / pz * fx + cx;
        const float v = py / pz * fy + cy;
        const bool inview = (u > 0.0f) && (u < (float)(W_IMG - 1)) &&
                            (v > 0.0f) && (v < (float)(H_IMG - 1));

        const float uf = fminf(fmaxf(rintf(u), 0.0f), (float)(W_IMG - 1));
        const float vf = fminf(fmaxf(rintf(v), 0.0f), (float)(H_IMG - 1));
        const int wbase = ((int)vf * W_IMG + (int)uf) * 3;

        const float r1x = vert1[wbase], r1y = vert1[wbase + 1], r1z = vert1[wbase + 2];
        const float m1x = norm1[wbase], m1y = norm1[wbase + 1], m1z = norm1[wbase + 2];

        const float dx = px - r1x, dy = py - r1y, dz = pz - r1z;
        const bool mask0 = v0z > 0.0f;
        const bool mask1 = r1z > 0.0f;
        const bool normal_ok = (nrx * m1x + nry * m1y + nrz * m1z) > NORM_THR;
        const float d2 = dx * dx + dy * dy + dz * dz;
        const bool occ = (!inview) || (d2 > DIST_THR2);
        const bool valid = (!occ) && mask0 && mask1 && normal_ok;

        if (valid) {
            const float res = m1x * dx + m1y * dy + m1z * dz;
            float J[6];
            J[0] = py * m1z - pz * m1y;
            J[1] = pz * m1x - px * m1z;
            J[2] = px * m1y - py * m1x;
            J[3] = m1x; J[4] = m1y; J[5] = m1z;
            int k = 0;
#pragma unroll
            for (int i = 0; i < 6; ++i)
#pragma unroll
                for (int j = i; j < 6; ++j) a[k++] += J[i] * J[j];
#pragma unroll
            for (int i = 0; i < 6; ++i) a[21 + i] += J[i] * res;
            a[27] += 1.0f;
        }
    };

    // exactly one quad (4 pixels) per thread
    const int q = blockIdx.x * RTPB + threadIdx.x;
    const float4* v0q = (const float4*)vert0;
    const float4* n0q = (const float4*)norm0;
    const float4 A0 = v0q[q * 3 + 0], A1 = v0q[q * 3 + 1], A2 = v0q[q * 3 + 2];
    const float4 B0 = n0q[q * 3 + 0], B1 = n0q[q * 3 + 1], B2 = n0q[q * 3 + 2];
    do_pixel(A0.x, A0.y, A0.z, B0.x, B0.y, B0.z);
    do_pixel(A0.w, A1.x, A1.y, B0.w, B1.x, B1.y);
    do_pixel(A1.z, A1.w, A2.x, B1.z, B1.w, B2.x);
    do_pixel(A2.y, A2.z, A2.w, B2.y, B2.z, B2.w);

    // wave-64 tree reduction per component
#pragma unroll
    for (int k = 0; k < NACC; ++k) {
        float val = a[k];
        for (int off = 32; off > 0; off >>= 1) val += __shfl_down(val, off, 64);
        a[k] = val;
    }

    __shared__ float sh[4][NACC];
    const int lane = threadIdx.x & 63;
    const int wid  = threadIdx.x >> 6;
    if (lane == 0) {
#pragma unroll
        for (int k = 0; k < NACC; ++k) sh[wid][k] = a[k];
    }
    __syncthreads();

    const int tid = threadIdx.x;
    if (tid < NACC) {
        // plain store of this block's partial; visible at kernel end (release)
        partials[blockIdx.x * NACC + tid] =
            sh[0][tid] + sh[1][tid] + sh[2][tid] + sh[3][tid];
    }
}

// ---------------------------------------------------------------------------
// solve: sum 1280x28 partials (f64), 6x6 damped solve + exp_se3 + pose update
// ---------------------------------------------------------------------------
__global__ __launch_bounds__(1024) void icp_solve(
    const float* __restrict__ partials, const float* __restrict__ pose0_f32,
    double* __restrict__ pose_ws, float* __restrict__ out,
    int first, int write_out)
{
    __shared__ double tot[NACC];

    const int tid = threadIdx.x;
    const int g = tid >> 5;        // component group (32 threads each)
    const int l = tid & 31;
    if (g < NACC) {
        double s = 0.0;
        for (int b = l; b < RBLOCKS; b += 32)
            s += (double)partials[b * NACC + g];
        // width-32 shuffle reduce (stays within half-wave groups)
        for (int off = 16; off > 0; off >>= 1)
            s += __shfl_down(s, off, 32);
        if (l == 0) tot[g] = s;
    }
    __syncthreads();
    if (tid != 0) return;

    double JtJ[6][6];
    {
        int k = 0;
        for (int i = 0; i < 6; ++i)
            for (int j = i; j < 6; ++j) { JtJ[i][j] = tot[k]; JtJ[j][i] = tot[k]; ++k; }
    }
    double tr = 0.0;
    for (int i = 0; i < 6; ++i) tr += JtJ[i][i];

    double A[6][7];
    for (int i = 0; i < 6; ++i) {
        for (int j = 0; j < 6; ++j) A[i][j] = JtJ[i][j] + (i == j ? tr * DAMPING : 0.0);
        A[i][6] = -tot[21 + i];
    }
    for (int c = 0; c < 6; ++c) {
        int piv = c; double mx = fabs(A[c][c]);
        for (int r = c + 1; r < 6; ++r) {
            double ar = fabs(A[r][c]);
            if (ar > mx) { mx = ar; piv = r; }
        }
        if (piv != c) for (int j = 0; j < 7; ++j) { double tmp = A[c][j]; A[c][j] = A[piv][j]; A[piv][j] = tmp; }
        double d = A[c][c]; if (d == 0.0) d = 1e-30;
        for (int r = c + 1; r < 6; ++r) {
            double f = A[r][c] / d;
            for (int j = c; j < 7; ++j) A[r][j] -= f * A[c][j];
        }
    }
    double xi[6];
    for (int i = 5; i >= 0; --i) {
        double s = A[i][6];
        for (int j = i + 1; j < 6; ++j) s -= A[i][j] * xi[j];
        double d = A[i][i]; if (d == 0.0) d = 1e-30;
        xi[i] = s / d;
    }

    const double w0 = xi[0], w1 = xi[1], w2 = xi[2];
    const double v0 = xi[3], v1 = xi[4], v2 = xi[5];
    double wh[3][3] = { {0.0, -w2, w1}, {w2, 0.0, -w0}, {-w1, w0, 0.0} };
    double wh2[3][3];
    for (int i = 0; i < 3; ++i)
        for (int j = 0; j < 3; ++j) {
            double s = 0.0;
            for (int k = 0; k < 3; ++k) s += wh[i][k] * wh[k][j];
            wh2[i][j] = s;
        }
    const double theta = sqrt(w0 * w0 + w1 * w1 + w2 * w2);
    const double eps = 1e-8;
    const double ts = (theta > eps) ? theta : eps;
    const double st = sin(ts), ct = cos(ts);
    const double cA = st / ts;
    const double cB = (1.0 - ct) / (ts * ts);
    const double cC = (ts - st) / (ts * ts * ts);
    const bool small = (theta <= eps);

    double ew[3][3], Jm[3][3];
    for (int i = 0; i < 3; ++i)
        for (int j = 0; j < 3; ++j) {
            double eye = (i == j) ? 1.0 : 0.0;
            ew[i][j] = small ? eye : (eye + cA * wh[i][j] + cB * wh2[i][j]);
            Jm[i][j] = small ? eye : (eye + cB * wh[i][j] + cC * wh2[i][j]);
        }
    double Jv[3];
    for (int i = 0; i < 3; ++i) Jv[i] = Jm[i][0] * v0 + Jm[i][1] * v1 + Jm[i][2] * v2;

    double T[16] = { ew[0][0], ew[0][1], ew[0][2], Jv[0],
                     ew[1][0], ew[1][1], ew[1][2], Jv[1],
                     ew[2][0], ew[2][1], ew[2][2], Jv[2],
                     0.0, 0.0, 0.0, 1.0 };
    double Pm[16];
    if (first) { for (int i = 0; i < 16; ++i) Pm[i] = (double)pose0_f32[i]; }
    else       { for (int i = 0; i < 16; ++i) Pm[i] = pose_ws[i]; }
    double NP[16];
    for (int i = 0; i < 4; ++i)
        for (int j = 0; j < 4; ++j) {
            double s = 0.0;
            for (int k = 0; k < 4; ++k) s += T[i * 4 + k] * Pm[k * 4 + j];
            NP[i * 4 + j] = s;
        }
    for (int i = 0; i < 16; ++i) pose_ws[i] = NP[i];

    if (write_out) {
        for (int i = 0; i < 16; ++i) out[i] = (float)NP[i];
        out[16] = (float)(tot[27] / (double)NPIX);
    }
}

// ---------------------------------------------------------------------------
extern "C" void kernel_launch(void* const* d_in, const int* in_sizes, int n_in,
                              void* d_out, int out_size, void* d_ws, size_t ws_size,
                              hipStream_t stream) {
    const float* pose10 = (const float*)d_in[0];
    const float* vert0  = (const float*)d_in[1];
    const float* vert1  = (const float*)d_in[2];
    const float* norm0  = (const float*)d_in[3];
    const float* norm1  = (const float*)d_in[4];
    const float* Kmat   = (const float*)d_in[5];
    float* out = (float*)d_out;

    double* pose_ws = (double*)d_ws;                 // 16 doubles
    float* partials = (float*)((double*)d_ws + 16);  // RBLOCKS*NACC floats

    for (int it = 0; it < 3; ++it) {
        const int first = (it == 0) ? 1 : 0;
        icp_reduce<<<RBLOCKS, RTPB, 0, stream>>>(vert0, vert1, norm0, norm1,
                                                 Kmat, pose10, pose_ws,
                                                 partials, first);
        icp_solve<<<1, 1024, 0, stream>>>(partials, pose10, pose_ws, out,
                                          first, it == 2 ? 1 : 0);
    }
}

// Round 7
// 196.437 us; speedup vs baseline: 1.3827x; 1.2403x over previous
//
#include <hip/hip_runtime.h>
#include <hip/hip_fp16.h>
#include <math.h>

typedef float fvec4 __attribute__((ext_vector_type(4)));

#define H_IMG 1024
#define W_IMG 1280
#define NPIX (H_IMG * W_IMG)
#define NQUAD (NPIX / 4)             // 327680
#define TPB 256
#define BLOCKS 640
#define QPT (NQUAD / (BLOCKS * TPB)) // 2 quads (8 px) per thread, exact
#define NACC 28                      // 21 JtJ upper-tri + 6 JtR + 1 count
#define NORM_THR 0.93969262f         // float(cos(20 deg))
#define DIST_THR2 0.04f              // 0.2^2
#define DAMPING 1e-6

// ws layout (bytes):
//   [0,384)       : 3 pose slots, 16 f64 each
//   [512, +3*71680): partials x3, component-major f32 [c*BLOCKS + b]
//   [262144, +NPIX*16): packed gather records {v1x,v1y,v1z, enc(n1)}
#define PART_OFF 512
#define PACKED_OFF 262144
#define WS_NEEDED (PACKED_OFF + (size_t)NPIX * 16)

// ---------------------------------------------------------------------------
// f16-pair normal encode/decode; nz sign stored in ny's LSB (n1 is unit norm)
__device__ inline float enc_n(float nx, float ny, float nz) {
    unsigned hx = __half_as_ushort(__float2half_rn(nx));
    unsigned hy = __half_as_ushort(__float2half_rn(ny)) & 0xFFFEu;
    hy |= (nz < 0.f) ? 1u : 0u;
    return __uint_as_float(hx | (hy << 16));
}
__device__ inline void dec_n(float w, float& nx, float& ny, float& nz) {
    unsigned u = __float_as_uint(w);
    nx = __half2float(__ushort_as_half((unsigned short)(u & 0xFFFFu)));
    unsigned short hy = (unsigned short)(u >> 16);
    ny = __half2float(__ushort_as_half((unsigned short)(hy & 0xFFFEu)));
    float s = (hy & 1u) ? -1.f : 1.f;
    nz = s * sqrtf(fmaxf(0.f, 1.f - nx * nx - ny * ny));
}

// ---------------------------------------------------------------------------
// 6x6 damped solve from tot[28] + exp_se3 + compose with base -> NP[16] (f64)
__device__ void solve_compose(const double* tot, const double* base, double* NP) {
    double JtJ[6][6];
    {
        int k = 0;
        for (int i = 0; i < 6; ++i)
            for (int j = i; j < 6; ++j) { JtJ[i][j] = tot[k]; JtJ[j][i] = tot[k]; ++k; }
    }
    double tr = 0.0;
    for (int i = 0; i < 6; ++i) tr += JtJ[i][i];

    double A[6][7];
    for (int i = 0; i < 6; ++i) {
        for (int j = 0; j < 6; ++j) A[i][j] = JtJ[i][j] + (i == j ? tr * DAMPING : 0.0);
        A[i][6] = -tot[21 + i];
    }
    for (int c = 0; c < 6; ++c) {
        int piv = c; double mx = fabs(A[c][c]);
        for (int r = c + 1; r < 6; ++r) {
            double ar = fabs(A[r][c]);
            if (ar > mx) { mx = ar; piv = r; }
        }
        if (piv != c) for (int j = 0; j < 7; ++j) { double t = A[c][j]; A[c][j] = A[piv][j]; A[piv][j] = t; }
        double d = A[c][c]; if (d == 0.0) d = 1e-30;
        for (int r = c + 1; r < 6; ++r) {
            double f = A[r][c] / d;
            for (int j = c; j < 7; ++j) A[r][j] -= f * A[c][j];
        }
    }
    double xi[6];
    for (int i = 5; i >= 0; --i) {
        double s = A[i][6];
        for (int j = i + 1; j < 6; ++j) s -= A[i][j] * xi[j];
        double d = A[i][i]; if (d == 0.0) d = 1e-30;
        xi[i] = s / d;
    }

    const double w0 = xi[0], w1 = xi[1], w2 = xi[2];
    const double v0 = xi[3], v1 = xi[4], v2 = xi[5];
    double wh[3][3] = { {0.0, -w2, w1}, {w2, 0.0, -w0}, {-w1, w0, 0.0} };
    double wh2[3][3];
    for (int i = 0; i < 3; ++i)
        for (int j = 0; j < 3; ++j) {
            double s = 0.0;
            for (int k = 0; k < 3; ++k) s += wh[i][k] * wh[k][j];
            wh2[i][j] = s;
        }
    const double theta = sqrt(w0 * w0 + w1 * w1 + w2 * w2);
    const double eps = 1e-8;
    const double ts = (theta > eps) ? theta : eps;
    const double st = sin(ts), ct = cos(ts);
    const double cA = st / ts;
    const double cB = (1.0 - ct) / (ts * ts);
    const double cC = (ts - st) / (ts * ts * ts);
    const bool small = (theta <= eps);

    double ew[3][3], Jm[3][3];
    for (int i = 0; i < 3; ++i)
        for (int j = 0; j < 3; ++j) {
            double eye = (i == j) ? 1.0 : 0.0;
            ew[i][j] = small ? eye : (eye + cA * wh[i][j] + cB * wh2[i][j]);
            Jm[i][j] = small ? eye : (eye + cB * wh[i][j] + cC * wh2[i][j]);
        }
    double Jv[3];
    for (int i = 0; i < 3; ++i) Jv[i] = Jm[i][0] * v0 + Jm[i][1] * v1 + Jm[i][2] * v2;

    double T[16] = { ew[0][0], ew[0][1], ew[0][2], Jv[0],
                     ew[1][0], ew[1][1], ew[1][2], Jv[1],
                     ew[2][0], ew[2][1], ew[2][2], Jv[2],
                     0.0, 0.0, 0.0, 1.0 };
    for (int i = 0; i < 4; ++i)
        for (int j = 0; j < 4; ++j) {
            double s = 0.0;
            for (int k = 0; k < 4; ++k) s += T[i * 4 + k] * base[k * 4 + j];
            NP[i * 4 + j] = s;
        }
}

// ---------------------------------------------------------------------------
// FIRST: pose from pose10; optionally (PACKED) build the packed gather table
//        while gathering raw. !FIRST: prologue solves prev iteration's system
//        redundantly per block; gather from packed (PACKED) or raw.
template<int FIRST, int PACKED>
__global__ __launch_bounds__(TPB) void icp_pass(
    const float* __restrict__ vert0, const float* __restrict__ vert1,
    const float* __restrict__ norm0, const float* __restrict__ norm1,
    const float* __restrict__ Kmat, const float* __restrict__ pose10,
    const double* __restrict__ pose_in, double* __restrict__ pose_out,
    const float* __restrict__ part_in, float* __restrict__ part_out,
    const fvec4* __restrict__ packedr, fvec4* __restrict__ packedw)
{
    const int tid = threadIdx.x;
    const int b = blockIdx.x;
    const int wid = tid >> 6, lane = tid & 63;

    __shared__ double ldpose[16];
    __shared__ double tot[NACC];

    if (FIRST) {
        if (tid < 16) {
            ldpose[tid] = (double)pose10[tid];
            if (b == 0) pose_out[tid] = (double)pose10[tid];
        }
    } else {
        // deterministic f64 sum of prev partials (identical in every block)
#pragma unroll
        for (int i = 0; i < 7; ++i) {
            const int c = wid * 7 + i;
            double s = 0.0;
#pragma unroll
            for (int j = 0; j < BLOCKS / 64; ++j)
                s += (double)part_in[c * BLOCKS + lane + 64 * j];
            for (int off = 32; off; off >>= 1) s += __shfl_down(s, off, 64);
            if (lane == 0) tot[c] = s;
        }
        __syncthreads();
        if (tid == 0) {
            double NP[16];
            solve_compose(tot, pose_in, NP);
            for (int i = 0; i < 16; ++i) ldpose[i] = NP[i];
            if (b == 0) for (int i = 0; i < 16; ++i) pose_out[i] = NP[i];
        }
    }
    __syncthreads();

    const float R00 = (float)ldpose[0],  R01 = (float)ldpose[1],  R02 = (float)ldpose[2],  t0 = (float)ldpose[3];
    const float R10 = (float)ldpose[4],  R11 = (float)ldpose[5],  R12 = (float)ldpose[6],  t1 = (float)ldpose[7];
    const float R20 = (float)ldpose[8],  R21 = (float)ldpose[9],  R22 = (float)ldpose[10], t2 = (float)ldpose[11];
    const float fx = Kmat[0], cx = Kmat[2], fy = Kmat[4], cy = Kmat[5];

    float a[NACC];
#pragma unroll
    for (int k = 0; k < NACC; ++k) a[k] = 0.0f;

    auto do_pixel = [&](float v0x, float v0y, float v0z,
                        float n0x, float n0y, float n0z) {
        const float px = R00 * v0x + R01 * v0y + R02 * v0z + t0;
        const float py = R10 * v0x + R11 * v0y + R12 * v0z + t1;
        const float pz = R20 * v0x + R21 * v0y + R22 * v0z + t2;
        const float nrx = R00 * n0x + R01 * n0y + R02 * n0z;
        const float nry = R10 * n0x + R11 * n0y + R12 * n0z;
        const float nrz = R20 * n0x + R21 * n0y + R22 * n0z;

        const float u = px / pz * fx + cx;
        const float v = py / pz * fy + cy;
        const bool inview = (u > 0.0f) && (u < (float)(W_IMG - 1)) &&
                            (v > 0.0f) && (v < (float)(H_IMG - 1));

        const float uf = fminf(fmaxf(rintf(u), 0.0f), (float)(W_IMG - 1));
        const float vf = fminf(fmaxf(rintf(v), 0.0f), (float)(H_IMG - 1));
        const int wpix = (int)vf * W_IMG + (int)uf;

        float r1x, r1y, r1z, m1x, m1y, m1z;
        if (PACKED && !FIRST) {
            const fvec4 g = packedr[wpix];     // one aligned 16B load / pixel
            r1x = g.x; r1y = g.y; r1z = g.z;
            dec_n(g.w, m1x, m1y, m1z);
        } else {
            const int wb = wpix * 3;
            r1x = vert1[wb]; r1y = vert1[wb + 1]; r1z = vert1[wb + 2];
            m1x = norm1[wb]; m1y = norm1[wb + 1]; m1z = norm1[wb + 2];
        }

        const float dx = px - r1x, dy = py - r1y, dz = pz - r1z;
        const bool mask0 = v0z > 0.0f;
        const bool mask1 = r1z > 0.0f;
        const bool normal_ok = (nrx * m1x + nry * m1y + nrz * m1z) > NORM_THR;
        const float d2 = dx * dx + dy * dy + dz * dz;
        const bool occ = (!inview) || (d2 > DIST_THR2);
        const bool valid = (!occ) && mask0 && mask1 && normal_ok;

        if (valid) {
            const float res = m1x * dx + m1y * dy + m1z * dz;
            float J[6];
            J[0] = py * m1z - pz * m1y;
            J[1] = pz * m1x - px * m1z;
            J[2] = px * m1y - py * m1x;
            J[3] = m1x; J[4] = m1y; J[5] = m1z;
            int k = 0;
#pragma unroll
            for (int i = 0; i < 6; ++i)
#pragma unroll
                for (int j = i; j < 6; ++j) a[k++] += J[i] * J[j];
#pragma unroll
            for (int i = 0; i < 6; ++i) a[21 + i] += J[i] * res;
            a[27] += 1.0f;
        }
    };

    // XCD-stripe swizzle: blocks on XCD x (b%8==x) cover one contiguous stripe
    const int region = (b & 7) * (BLOCKS / 8) + (b >> 3);
    const fvec4* v0q = (const fvec4*)vert0;
    const fvec4* n0q = (const fvec4*)norm0;
    const fvec4* v1q = (const fvec4*)vert1;
    const fvec4* n1q = (const fvec4*)norm1;

#pragma unroll
    for (int k = 0; k < QPT; ++k) {
        const int q = region * (TPB * QPT) + tid + k * TPB;

        if (FIRST && PACKED) {
            // build packed table (v1/n1 read exactly once ever -> nontemporal)
            const fvec4 V0 = __builtin_nontemporal_load(&v1q[q * 3 + 0]);
            const fvec4 V1 = __builtin_nontemporal_load(&v1q[q * 3 + 1]);
            const fvec4 V2 = __builtin_nontemporal_load(&v1q[q * 3 + 2]);
            const fvec4 N0 = __builtin_nontemporal_load(&n1q[q * 3 + 0]);
            const fvec4 N1 = __builtin_nontemporal_load(&n1q[q * 3 + 1]);
            const fvec4 N2 = __builtin_nontemporal_load(&n1q[q * 3 + 2]);
            const int p = q * 4;
            packedw[p + 0] = (fvec4){V0.x, V0.y, V0.z, enc_n(N0.x, N0.y, N0.z)};
            packedw[p + 1] = (fvec4){V0.w, V1.x, V1.y, enc_n(N0.w, N1.x, N1.y)};
            packedw[p + 2] = (fvec4){V1.z, V1.w, V2.x, enc_n(N1.z, N1.w, N2.x)};
            packedw[p + 3] = (fvec4){V2.y, V2.z, V2.w, enc_n(N2.y, N2.z, N2.w)};
        }

        const fvec4 A0 = v0q[q * 3 + 0], A1 = v0q[q * 3 + 1], A2 = v0q[q * 3 + 2];
        const fvec4 B0 = n0q[q * 3 + 0], B1 = n0q[q * 3 + 1], B2 = n0q[q * 3 + 2];
        do_pixel(A0.x, A0.y, A0.z, B0.x, B0.y, B0.z);
        do_pixel(A0.w, A1.x, A1.y, B0.w, B1.x, B1.y);
        do_pixel(A1.z, A1.w, A2.x, B1.z, B1.w, B2.x);
        do_pixel(A2.y, A2.z, A2.w, B2.y, B2.z, B2.w);
    }

    // block reduction -> component-major partials
#pragma unroll
    for (int k = 0; k < NACC; ++k) {
        float val = a[k];
        for (int off = 32; off > 0; off >>= 1) val += __shfl_down(val, off, 64);
        a[k] = val;
    }
    __shared__ float sh[4][NACC];
    if (lane == 0) {
#pragma unroll
        for (int k = 0; k < NACC; ++k) sh[wid][k] = a[k];
    }
    __syncthreads();
    if (tid < NACC)
        part_out[tid * BLOCKS + b] = sh[0][tid] + sh[1][tid] + sh[2][tid] + sh[3][tid];
}

// ---------------------------------------------------------------------------
__global__ __launch_bounds__(TPB) void icp_final(
    const float* __restrict__ part_in, const double* __restrict__ pose_in,
    float* __restrict__ out)
{
    __shared__ double tot[NACC];
    const int tid = threadIdx.x;
    const int wid = tid >> 6, lane = tid & 63;
#pragma unroll
    for (int i = 0; i < 7; ++i) {
        const int c = wid * 7 + i;
        double s = 0.0;
#pragma unroll
        for (int j = 0; j < BLOCKS / 64; ++j)
            s += (double)part_in[c * BLOCKS + lane + 64 * j];
        for (int off = 32; off; off >>= 1) s += __shfl_down(s, off, 64);
        if (lane == 0) tot[c] = s;
    }
    __syncthreads();
    if (tid == 0) {
        double NP[16];
        solve_compose(tot, pose_in, NP);
        for (int i = 0; i < 16; ++i) out[i] = (float)NP[i];
        out[16] = (float)(tot[27] / (double)NPIX);
    }
}

// ---------------------------------------------------------------------------
extern "C" void kernel_launch(void* const* d_in, const int* in_sizes, int n_in,
                              void* d_out, int out_size, void* d_ws, size_t ws_size,
                              hipStream_t stream) {
    const float* pose10 = (const float*)d_in[0];
    const float* vert0  = (const float*)d_in[1];
    const float* vert1  = (const float*)d_in[2];
    const float* norm0  = (const float*)d_in[3];
    const float* norm1  = (const float*)d_in[4];
    const float* Kmat   = (const float*)d_in[5];
    float* out = (float*)d_out;

    double* pose_s0 = (double*)d_ws;
    double* pose_s1 = pose_s0 + 16;
    double* pose_s2 = pose_s0 + 32;
    float* part0 = (float*)((char*)d_ws + PART_OFF);
    float* part1 = part0 + BLOCKS * NACC;
    float* part2 = part1 + BLOCKS * NACC;
    fvec4* packed = (fvec4*)((char*)d_ws + PACKED_OFF);

    if (ws_size >= WS_NEEDED) {
        icp_pass<1, 1><<<BLOCKS, TPB, 0, stream>>>(vert0, vert1, norm0, norm1, Kmat, pose10,
                                                   nullptr, pose_s0, nullptr, part0,
                                                   nullptr, packed);
        icp_pass<0, 1><<<BLOCKS, TPB, 0, stream>>>(vert0, vert1, norm0, norm1, Kmat, pose10,
                                                   pose_s0, pose_s1, part0, part1,
                                                   packed, nullptr);
        icp_pass<0, 1><<<BLOCKS, TPB, 0, stream>>>(vert0, vert1, norm0, norm1, Kmat, pose10,
                                                   pose_s1, pose_s2, part1, part2,
                                                   packed, nullptr);
    } else {
        icp_pass<1, 0><<<BLOCKS, TPB, 0, stream>>>(vert0, vert1, norm0, norm1, Kmat, pose10,
                                                   nullptr, pose_s0, nullptr, part0,
                                                   nullptr, nullptr);
        icp_pass<0, 0><<<BLOCKS, TPB, 0, stream>>>(vert0, vert1, norm0, norm1, Kmat, pose10,
                                                   pose_s0, pose_s1, part0, part1,
                                                   nullptr, nullptr);
        icp_pass<0, 0><<<BLOCKS, TPB, 0, stream>>>(vert0, vert1, norm0, norm1, Kmat, pose10,
                                                   pose_s1, pose_s2, part1, part2,
                                                   nullptr, nullptr);
    }
    icp_final<<<1, TPB, 0, stream>>>(part2, pose_s2, out);
}